// Round 9
// baseline (860.844 us; speedup 1.0000x reference)
//
#include <hip/hip_runtime.h>
#include <hip/hip_bf16.h>

#define NN  20000
#define NE  320000
#define FIN 256
#define FH  512

typedef __attribute__((ext_vector_type(8))) short bf16x8;
typedef __attribute__((ext_vector_type(4))) float f32x4;
typedef __attribute__((ext_vector_type(4))) unsigned short u16x4;
typedef __attribute__((ext_vector_type(4))) unsigned int u32x4;

static __device__ __forceinline__ unsigned short f2b(float f) {
    union { float f; unsigned int i; } v; v.f = f;
    return (unsigned short)((v.i + 0x7fffu + ((v.i >> 16) & 1u)) >> 16);
}
static __device__ __forceinline__ f32x4 mfma16(bf16x8 a, bf16x8 b, f32x4 c) {
    return __builtin_amdgcn_mfma_f32_16x16x32_bf16(a, b, c, 0, 0, 0);
}
// 2x f32 -> packed bf16 pair (lowers to v_cvt_pk_bf16_f32), RNE
static __device__ __forceinline__ unsigned int cvtpk(float lo, float hi) {
    union { __hip_bfloat162 h; unsigned int u; } v;
    v.h = __float22bfloat162_rn(float2{lo, hi});
    return v.u;
}
static __device__ __forceinline__ u16x4 pack4(float a, float b, float c, float d) {
    union { u16x4 s; unsigned int u[2]; } v;
    v.u[0] = cvtpk(a, b); v.u[1] = cvtpk(c, d);
    return v.s;
}
static __device__ __forceinline__ bf16x8 cvt8(f32x4 a, f32x4 b) {
    u32x4 t;
    t[0] = cvtpk(a[0], a[1]);
    t[1] = cvtpk(a[2], a[3]);
    t[2] = cvtpk(b[0], b[1]);
    t[3] = cvtpk(b[2], b[3]);
    return __builtin_bit_cast(bf16x8, t);
}

// ------------------------------------------------- fused prep (one kernel)
// 256 blocks x 1024 threads, all co-resident (16 waves/block, <=2 blocks/CU
// capacity). Grid barriers via device-scope atomic counters; counters are
// zeroed by the per-replay memset, so graph capture/replay is safe.
static __device__ __forceinline__ void gridbar(int* ctr, int nblk) {
    __syncthreads();
    if (threadIdx.x == 0) {
        __threadfence();
        atomicAdd(ctr, 1);
        while (atomicAdd(ctr, 0) < nblk) __builtin_amdgcn_s_sleep(1);
    }
    __syncthreads();
}

__global__ void __launch_bounds__(1024, 1)
prep_all(const float* __restrict__ We1, const float* __restrict__ We2,
         const float* __restrict__ Wn1, const float* __restrict__ Wn2,
         const int* __restrict__ dstI,
         unsigned short* __restrict__ W1F, unsigned short* __restrict__ W2F,
         unsigned short* __restrict__ Wn1F, unsigned short* __restrict__ Wn2F,
         int* __restrict__ cnt, int* __restrict__ gbar,
         int* __restrict__ bsum, int* __restrict__ bbase,
         int* __restrict__ cursor, int* __restrict__ perm)
{
    const int tid = threadIdx.x;
    const int b   = blockIdx.x;

    // ---- phase 0: fragment-major weight transpose+cvt (wave-per-fragment).
    // frag f = n_frag*(K/32)+ks is a 1KB blob; 16B chunk at (f*64+lane)*8
    // holds W^T[n_frag*16+(lane&15)][ks*32+(lane>>4)*8+j].
    {
        const int gw = b * 16 + (tid >> 6);    // global wave id, 4096 total
        if (gw < 1024) {
            const int m = gw >> 8, f = gw & 255;
            const float* src; unsigned short* dst; int N, K;
            if      (m == 0) { src = We1; dst = W1F;  N = 512; K = 256; }
            else if (m == 1) { src = We2; dst = W2F;  N = 256; K = 512; }
            else if (m == 2) { src = Wn1; dst = Wn1F; N = 512; K = 256; }
            else             { src = Wn2; dst = Wn2F; N = 256; K = 512; }
            const int KB = K >> 5;
            const int nf = f / KB, ks = f % KB;
            const int l  = tid & 63;
            const int n  = nf * 16 + (l & 15);
            const int k0 = ks * 32 + (l >> 4) * 8;
            f32x4 a, c;
            #pragma unroll
            for (int j = 0; j < 4; ++j) {
                a[j] = src[(size_t)(k0 + j) * N + n];      // src is [K][N]
                c[j] = src[(size_t)(k0 + 4 + j) * N + n];
            }
            *(bf16x8*)(dst + ((size_t)f * 64 + l) * 8) = cvt8(a, c);
        }
    }

    // ---- phase 0b: histogram of dst
    for (int e = b * 1024 + tid; e < NE; e += 256 * 1024)
        atomicAdd(&cnt[dstI[e]], 1);
    gridbar(gbar + 0, 256);

    // ---- phase 1: per-block sums of cnt[b*80 .. b*80+80)
    __shared__ int ls[80];
    __shared__ int ss[256];
    const int lo = b * 80;
    const int hi = (lo + 80 <= NN) ? 80 : ((NN > lo) ? NN - lo : 0);
    if (tid < hi) ls[tid] = atomicAdd(&cnt[lo + tid], 0);  // coherent read
    __syncthreads();
    if (tid == 0) {
        int s = 0;
        for (int i = 0; i < hi; ++i) s += ls[i];
        atomicExch(&bsum[b], s);
    }
    gridbar(gbar + 1, 256);

    // ---- phase 2: block 0 scans the 256 block sums (exclusive)
    if (b == 0) {
        int v = 0;
        if (tid < 256) { v = atomicAdd(&bsum[tid], 0); ss[tid] = v; }
        __syncthreads();
        for (int off = 1; off < 256; off <<= 1) {
            int t = 0;
            if (tid < 256 && tid >= off) t = ss[tid - off];
            __syncthreads();
            if (tid < 256) ss[tid] += t;
            __syncthreads();
        }
        if (tid < 256) atomicExch(&bbase[tid], ss[tid] - v);
    }
    gridbar(gbar + 2, 256);

    // ---- phase 3: per-block exclusive scan -> cursor
    if (tid == 0 && hi > 0) {
        int base = atomicAdd(&bbase[b], 0);
        for (int i = 0; i < hi; ++i) { int c = ls[i]; cursor[lo + i] = base; base += c; }
        __threadfence();
    }
    gridbar(gbar + 3, 256);

    // ---- phase 4: scatter permutation
    for (int e = b * 1024 + tid; e < NE; e += 256 * 1024) {
        int pos = atomicAdd(&cursor[dstI[e]], 1);
        perm[pos] = e;
    }
}

// ---------------------------------------------------------------- edge MLP
// R7-proven best: 512 threads / 64-edge tile, fragment-major W (coalesced
// 1KB weight loads), per-thread perm staging, nf prefetch in the acc1-dead
// register window, setprio around MFMA. 2 blocks/CU (66KB LDS union),
// exactly at the 128-reg/wave occupancy point.
__global__ void __launch_bounds__(512, 4)
gine_edge(const float* __restrict__ edge_feat,
          const float* __restrict__ node_feat,
          const int* __restrict__ srcI,
          const int* __restrict__ dstI,
          const int* __restrict__ perm,
          const unsigned short* __restrict__ W1F,   // fragment-major [256 frags][1KB]
          const float* __restrict__ b1,             // [512]
          const unsigned short* __restrict__ W2F,   // fragment-major [256 frags][1KB]
          const float* __restrict__ b2,             // [256]
          float* __restrict__ out_h)                // [NN,256] fp32 accum
{
    __shared__ union {
        unsigned short Xs[64 * 264];   // staged bf16 input, +8 pad
        unsigned short Hs[64 * 512];   // XOR-swizzled hidden
        float          Msg[64 * 260];  // fp32 messages, +4 pad
    } sh;
    __shared__ int snS[64], dnS[64];

    const int tid  = threadIdx.x;
    const int wave = tid >> 6;       // 0..7
    const int lane = tid & 63;
    const int quad = lane >> 4;
    const int ln   = lane & 15;
    const int bs   = (blockIdx.x & 7) * 625 + (blockIdx.x >> 3);
    const int e0   = bs * 64;

    // ---- stage gathered edge_feat rows -> bf16 LDS (per-thread perm read)
    #pragma unroll
    for (int it = 0; it < 4; ++it) {
        const int chunk = tid + it * 512;          // 2048 chunks of 8 elems
        const int row = chunk >> 5;
        const int c8  = (chunk & 31) << 3;
        const int e   = perm[e0 + row];            // broadcast across 32 threads
        const float* p = edge_feat + (size_t)e * FIN + c8;
        f32x4 o0 = *(const f32x4*)(p);
        f32x4 o1 = *(const f32x4*)(p + 4);
        *(bf16x8*)(&sh.Xs[row * 264 + c8]) = cvt8(o0, o1);
    }
    if (tid < 64) {
        const int e = perm[e0 + tid];
        snS[tid] = srcI[e];
        dnS[tid] = dstI[e];
    }
    __syncthreads();

    // ---- layer 1 (swapped): D1[n][edge]; 8 waves x 64-wide N slices
    f32x4 zero4 = {0.f, 0.f, 0.f, 0.f};
    f32x4 acc1[4][4];                              // [n-tile][edge-tile]
    #pragma unroll
    for (int nt = 0; nt < 4; ++nt)
        #pragma unroll
        for (int et = 0; et < 4; ++et) acc1[nt][et] = zero4;

    __builtin_amdgcn_s_setprio(1);
    #pragma unroll
    for (int ks = 0; ks < 8; ++ks) {
        bf16x8 w[4], x[4];
        #pragma unroll
        for (int nt = 0; nt < 4; ++nt)            // frag (wave*4+nt, ks): 1KB lane-linear
            w[nt] = *(const bf16x8*)(W1F + (((wave * 4 + nt) * 8 + ks) * 64 + lane) * 8);
        #pragma unroll
        for (int et = 0; et < 4; ++et)
            x[et] = *(const bf16x8*)(&sh.Xs[(et * 16 + ln) * 264 + quad * 8 + ks * 32]);
        #pragma unroll
        for (int nt = 0; nt < 4; ++nt)
            #pragma unroll
            for (int et = 0; et < 4; ++et)
                acc1[nt][et] = mfma16(w[nt], x[et], acc1[nt][et]);
    }
    __builtin_amdgcn_s_setprio(0);
    __syncthreads();   // done reading Xs before overwriting Hs

    // bias + relu -> packed bf16x4 -> swizzled LDS
    #pragma unroll
    for (int nt = 0; nt < 4; ++nt) {
        const int n0 = wave * 64 + nt * 16 + quad * 4;     // 4 consecutive n
        const f32x4 b4 = *(const f32x4*)(b1 + n0);
        #pragma unroll
        for (int et = 0; et < 4; ++et) {
            const int edge = et * 16 + ln;
            u16x4 p = pack4(fmaxf(acc1[nt][et][0] + b4[0], 0.f),
                            fmaxf(acc1[nt][et][1] + b4[1], 0.f),
                            fmaxf(acc1[nt][et][2] + b4[2], 0.f),
                            fmaxf(acc1[nt][et][3] + b4[3], 0.f));
            *(u16x4*)(&sh.Hs[(edge << 9) + (((n0 >> 3) ^ (edge & 7)) << 3) + (n0 & 7)]) = p;
        }
    }
    __syncthreads();

    // ---- nf prefetch (T14): issue gathers now, consume after L2 MFMA.
    // acc1 is dead here, so the 32 VGPRs fit in its window.
    f32x4 nfr[2][4];
    #pragma unroll
    for (int nt = 0; nt < 2; ++nt) {
        const int n0 = wave * 32 + nt * 16 + quad * 4;
        #pragma unroll
        for (int et = 0; et < 4; ++et) {
            const int sn = snS[et * 16 + ln];
            nfr[nt][et] = *(const f32x4*)(node_feat + (size_t)sn * FIN + n0);
        }
    }

    // ---- layer 2 (swapped): D2[n][edge]; 8 waves x 32-wide N slices
    f32x4 acc2[2][4];                              // [n-tile][edge-tile]
    #pragma unroll
    for (int nt = 0; nt < 2; ++nt)
        #pragma unroll
        for (int et = 0; et < 4; ++et) acc2[nt][et] = zero4;

    __builtin_amdgcn_s_setprio(1);
    #pragma unroll
    for (int ks = 0; ks < 16; ++ks) {
        const int kb = ks * 4 + quad;
        bf16x8 w[2], h[4];
        #pragma unroll
        for (int nt = 0; nt < 2; ++nt)            // frag (wave*2+nt, ks)
            w[nt] = *(const bf16x8*)(W2F + (((wave * 2 + nt) * 16 + ks) * 64 + lane) * 8);
        #pragma unroll
        for (int et = 0; et < 4; ++et) {
            const int edge = et * 16 + ln;
            h[et] = *(const bf16x8*)(&sh.Hs[(edge << 9) + ((kb ^ (edge & 7)) << 3)]);
        }
        #pragma unroll
        for (int nt = 0; nt < 2; ++nt)
            #pragma unroll
            for (int et = 0; et < 4; ++et)
                acc2[nt][et] = mfma16(w[nt], h[et], acc2[nt][et]);
    }
    __builtin_amdgcn_s_setprio(0);
    __syncthreads();   // done reading Hs before overwriting Msg

    // ---- epilogue 1: msg = relu(nf + E) -> LDS (fp32), nf from prefetch regs
    #pragma unroll
    for (int nt = 0; nt < 2; ++nt) {
        const int n0 = wave * 32 + nt * 16 + quad * 4;
        const f32x4 b4 = *(const f32x4*)(b2 + n0);
        #pragma unroll
        for (int et = 0; et < 4; ++et) {
            const int edge = et * 16 + ln;
            f32x4 m;
            #pragma unroll
            for (int r = 0; r < 4; ++r)
                m[r] = fmaxf(nfr[nt][et][r] + acc2[nt][et][r] + b4[r], 0.f);
            *(f32x4*)(&sh.Msg[edge * 260 + n0]) = m;
        }
    }
    __syncthreads();

    // ---- epilogue 2: run-length reduce over sorted dst rows; 512 threads =
    // 2 half-scans of 32 rows per column. Runs touching a half boundary use
    // atomicAdd (correct vs zero-init); interior runs are exclusive -> store.
    {
        const int col  = tid & 255;
        const int half = tid >> 8;
        const int rA   = half * 32;
        const int dF = dnS[rA], dL = dnS[rA + 31];
        float run = sh.Msg[rA * 260 + col];
        int cur = dF;
        #pragma unroll 4
        for (int row = rA + 1; row < rA + 32; ++row) {
            const int d = dnS[row];
            if (d != cur) {
                if (cur == dF || cur == dL)
                    atomicAdd(&out_h[(size_t)cur * FIN + col], run);
                else
                    out_h[(size_t)cur * FIN + col] = run;
                run = 0.f;
                cur = d;
            }
            run += sh.Msg[row * 260 + col];
        }
        atomicAdd(&out_h[(size_t)cur * FIN + col], run);   // cur == dL
    }
}

// ---------------------------------------------------------------- node MLP
__global__ void __launch_bounds__(512, 4)
gine_node(const float* __restrict__ node_feat,
          const float* __restrict__ out_h,
          const unsigned short* __restrict__ W1F,   // fragment-major
          const float* __restrict__ b1,
          const unsigned short* __restrict__ W2F,   // fragment-major
          const float* __restrict__ b2,
          const float* __restrict__ eps,
          float* __restrict__ out)
{
    __shared__ union {
        unsigned short Xs[64 * 264];
        unsigned short Hs[64 * 512];
    } sh;

    const int tid  = threadIdx.x;
    const int wave = tid >> 6;       // 0..7
    const int lane = tid & 63;
    const int quad = lane >> 4;
    const int ln   = lane & 15;
    const int n0b  = blockIdx.x * 64;
    const float epsv = 1.0f + eps[0];

    // stage x = (1+eps)*node_feat + out_h  -> bf16 LDS
    #pragma unroll
    for (int it = 0; it < 4; ++it) {
        const int chunk = tid + it * 512;
        const int row = chunk >> 5;
        const int c8  = (chunk & 31) << 3;
        const int g   = n0b + row;
        bf16x8 pack = {0, 0, 0, 0, 0, 0, 0, 0};
        if (g < NN) {
            const float* pn = node_feat + (size_t)g * FIN + c8;
            const float* ph = out_h + (size_t)g * FIN + c8;
            f32x4 n0v = *(const f32x4*)(pn);
            f32x4 n1v = *(const f32x4*)(pn + 4);
            f32x4 h0v = *(const f32x4*)(ph);
            f32x4 h1v = *(const f32x4*)(ph + 4);
            f32x4 a, b;
            #pragma unroll
            for (int j = 0; j < 4; ++j) {
                a[j] = epsv * n0v[j] + h0v[j];
                b[j] = epsv * n1v[j] + h1v[j];
            }
            pack = cvt8(a, b);
        }
        *(bf16x8*)(&sh.Xs[row * 264 + c8]) = pack;
    }
    __syncthreads();

    // ---- layer 1 (swapped)
    f32x4 zero4 = {0.f, 0.f, 0.f, 0.f};
    f32x4 acc1[4][4];
    #pragma unroll
    for (int nt = 0; nt < 4; ++nt)
        #pragma unroll
        for (int et = 0; et < 4; ++et) acc1[nt][et] = zero4;

    __builtin_amdgcn_s_setprio(1);
    #pragma unroll
    for (int ks = 0; ks < 8; ++ks) {
        bf16x8 w[4], xv[4];
        #pragma unroll
        for (int nt = 0; nt < 4; ++nt)
            w[nt] = *(const bf16x8*)(W1F + (((wave * 4 + nt) * 8 + ks) * 64 + lane) * 8);
        #pragma unroll
        for (int et = 0; et < 4; ++et)
            xv[et] = *(const bf16x8*)(&sh.Xs[(et * 16 + ln) * 264 + quad * 8 + ks * 32]);
        #pragma unroll
        for (int nt = 0; nt < 4; ++nt)
            #pragma unroll
            for (int et = 0; et < 4; ++et)
                acc1[nt][et] = mfma16(w[nt], xv[et], acc1[nt][et]);
    }
    __builtin_amdgcn_s_setprio(0);
    __syncthreads();

    #pragma unroll
    for (int nt = 0; nt < 4; ++nt) {
        const int n0 = wave * 64 + nt * 16 + quad * 4;
        const f32x4 b4 = *(const f32x4*)(b1 + n0);
        #pragma unroll
        for (int et = 0; et < 4; ++et) {
            const int edge = et * 16 + ln;
            u16x4 p = pack4(fmaxf(acc1[nt][et][0] + b4[0], 0.f),
                            fmaxf(acc1[nt][et][1] + b4[1], 0.f),
                            fmaxf(acc1[nt][et][2] + b4[2], 0.f),
                            fmaxf(acc1[nt][et][3] + b4[3], 0.f));
            *(u16x4*)(&sh.Hs[(edge << 9) + (((n0 >> 3) ^ (edge & 7)) << 3) + (n0 & 7)]) = p;
        }
    }
    __syncthreads();

    // ---- layer 2 (swapped)
    f32x4 acc2[2][4];
    #pragma unroll
    for (int nt = 0; nt < 2; ++nt)
        #pragma unroll
        for (int et = 0; et < 4; ++et) acc2[nt][et] = zero4;

    __builtin_amdgcn_s_setprio(1);
    #pragma unroll
    for (int ks = 0; ks < 16; ++ks) {
        const int kb = ks * 4 + quad;
        bf16x8 w[2], h[4];
        #pragma unroll
        for (int nt = 0; nt < 2; ++nt)
            w[nt] = *(const bf16x8*)(W2F + (((wave * 2 + nt) * 16 + ks) * 64 + lane) * 8);
        #pragma unroll
        for (int et = 0; et < 4; ++et) {
            const int edge = et * 16 + ln;
            h[et] = *(const bf16x8*)(&sh.Hs[(edge << 9) + ((kb ^ (edge & 7)) << 3)]);
        }
        #pragma unroll
        for (int nt = 0; nt < 2; ++nt)
            #pragma unroll
            for (int et = 0; et < 4; ++et)
                acc2[nt][et] = mfma16(w[nt], h[et], acc2[nt][et]);
    }
    __builtin_amdgcn_s_setprio(0);

    // C-write: 16-B vector stores
    #pragma unroll
    for (int nt = 0; nt < 2; ++nt) {
        const int n0 = wave * 32 + nt * 16 + quad * 4;
        const f32x4 b4 = *(const f32x4*)(b2 + n0);
        #pragma unroll
        for (int et = 0; et < 4; ++et) {
            const int g = n0b + et * 16 + ln;
            if (g < NN) {
                f32x4 o;
                #pragma unroll
                for (int r = 0; r < 4; ++r)
                    o[r] = acc2[nt][et][r] + b4[r];
                *(f32x4*)(out + (size_t)g * FIN + n0) = o;
            }
        }
    }
}

// ---------------------------------------------------------------- launch
extern "C" void kernel_launch(void* const* d_in, const int* in_sizes, int n_in,
                              void* d_out, int out_size, void* d_ws, size_t ws_size,
                              hipStream_t stream) {
    const float* node_feat = (const float*)d_in[0];
    const float* edge_feat = (const float*)d_in[1];
    const int* srcI = (const int*)d_in[2];
    const int* dstI = (const int*)d_in[3];
    const float* We1 = (const float*)d_in[4];
    const float* be1 = (const float*)d_in[5];
    const float* We2 = (const float*)d_in[6];
    const float* be2 = (const float*)d_in[7];
    const float* Wn1 = (const float*)d_in[8];
    const float* bn1 = (const float*)d_in[9];
    const float* Wn2 = (const float*)d_in[10];
    const float* bn2 = (const float*)d_in[11];
    const float* eps = (const float*)d_in[12];

    char* ws = (char*)d_ws;
    float* out_h = (float*)ws;                                  // 20,480,000 B
    unsigned short* W1F  = (unsigned short*)(ws + 20480000);    // 256 KB each
    unsigned short* W2F  = W1F + 131072;
    unsigned short* Wn1F = W2F + 131072;
    unsigned short* Wn2F = Wn1F + 131072;
    int* cnt    = (int*)(ws + 20480000 + 4 * 262144);           // NN ints
    int* gbar   = cnt + NN;                                     // 8 ints
    int* bsum   = gbar + 8;                                     // 256 ints
    int* bbase  = bsum + 256;                                   // 256 ints
    int* cursor = bbase + 256;                                  // NN ints
    int* perm   = cursor + NN;                                  // NE ints

    hipMemsetAsync(out_h, 0, (size_t)NN * FIN * sizeof(float), stream);
    hipMemsetAsync(cnt, 0, (NN + 8) * sizeof(int), stream);     // cnt + gbar

    prep_all<<<256, 1024, 0, stream>>>(We1, We2, Wn1, Wn2, dstI,
                                       W1F, W2F, Wn1F, Wn2F,
                                       cnt, gbar, bsum, bbase, cursor, perm);

    gine_edge<<<NE / 64, 512, 0, stream>>>(edge_feat, node_feat, srcI, dstI,
                                           perm, W1F, be1, W2F, be2, out_h);
    gine_node<<<(NN + 63) / 64, 512, 0, stream>>>(node_feat, out_h, Wn1F, bn1,
                                                  Wn2F, bn2, eps, (float*)d_out);
}

// Round 10
// 818.954 us; speedup vs baseline: 1.0512x; 1.0512x over previous
//
#include <hip/hip_runtime.h>
#include <hip/hip_bf16.h>

#define NN  20000
#define NE  320000
#define FIN 256
#define FH  512

typedef __attribute__((ext_vector_type(8))) short bf16x8;
typedef __attribute__((ext_vector_type(4))) float f32x4;
typedef __attribute__((ext_vector_type(4))) unsigned short u16x4;
typedef __attribute__((ext_vector_type(4))) unsigned int u32x4;

static __device__ __forceinline__ unsigned short f2b(float f) {
    union { float f; unsigned int i; } v; v.f = f;
    return (unsigned short)((v.i + 0x7fffu + ((v.i >> 16) & 1u)) >> 16);
}
static __device__ __forceinline__ f32x4 mfma16(bf16x8 a, bf16x8 b, f32x4 c) {
    return __builtin_amdgcn_mfma_f32_16x16x32_bf16(a, b, c, 0, 0, 0);
}
// 2x f32 -> packed bf16 pair (lowers to v_cvt_pk_bf16_f32), RNE
static __device__ __forceinline__ unsigned int cvtpk(float lo, float hi) {
    union { __hip_bfloat162 h; unsigned int u; } v;
    v.h = __float22bfloat162_rn(float2{lo, hi});
    return v.u;
}
static __device__ __forceinline__ u16x4 pack4(float a, float b, float c, float d) {
    union { u16x4 s; unsigned int u[2]; } v;
    v.u[0] = cvtpk(a, b); v.u[1] = cvtpk(c, d);
    return v.s;
}
static __device__ __forceinline__ bf16x8 cvt8(f32x4 a, f32x4 b) {
    u32x4 t;
    t[0] = cvtpk(a[0], a[1]);
    t[1] = cvtpk(a[2], a[3]);
    t[2] = cvtpk(b[0], b[1]);
    t[3] = cvtpk(b[2], b[3]);
    return __builtin_bit_cast(bf16x8, t);
}

// ---------------------------------- fused weight-prep + dst histogram
// 1280 blocks x 256 threads. Blocks 0..1023: first wave (64 threads) emits
// one fragment-major weight blob (frag f = n_frag*(K/32)+ks; 16B chunk at
// (f*64+lane)*8 holds W^T[n_frag*16+(lane&15)][ks*32+(lane>>4)*8+j]).
// ALL blocks: one histogram slice (1280*256 >= NE, single pass).
__global__ void prep_hist(const float* __restrict__ We1, const float* __restrict__ We2,
                          const float* __restrict__ Wn1, const float* __restrict__ Wn2,
                          const int* __restrict__ dstI,
                          unsigned short* __restrict__ W1F, unsigned short* __restrict__ W2F,
                          unsigned short* __restrict__ Wn1F, unsigned short* __restrict__ Wn2F,
                          int* __restrict__ cnt) {
    const int b   = blockIdx.x;
    const int tid = threadIdx.x;
    if (b < 1024 && tid < 64) {
        const int m = b >> 8, f = b & 255;
        const float* src; unsigned short* dst; int N, K;
        if      (m == 0) { src = We1; dst = W1F;  N = 512; K = 256; }
        else if (m == 1) { src = We2; dst = W2F;  N = 256; K = 512; }
        else if (m == 2) { src = Wn1; dst = Wn1F; N = 512; K = 256; }
        else             { src = Wn2; dst = Wn2F; N = 256; K = 512; }
        const int KB = K >> 5;
        const int nf = f / KB, ks = f % KB;
        const int n  = nf * 16 + (tid & 15);
        const int k0 = ks * 32 + (tid >> 4) * 8;
        f32x4 a, c;
        #pragma unroll
        for (int j = 0; j < 4; ++j) {
            a[j] = src[(size_t)(k0 + j) * N + n];         // src is [K][N]
            c[j] = src[(size_t)(k0 + 4 + j) * N + n];
        }
        *(bf16x8*)(dst + ((size_t)f * 64 + tid) * 8) = cvt8(a, c);
    }
    const int e = b * 256 + tid;
    if (e < NE) atomicAdd(&cnt[dstI[e]], 1);
}

// ------------------------------------------------- sort-by-dst prep
__global__ void scan_excl(const int* __restrict__ cnt, int* __restrict__ cursor) {
    __shared__ int c[NN];          // 80 KB
    __shared__ int s[1024];
    const int t = threadIdx.x;
    for (int i = t; i < NN; i += 1024) c[i] = cnt[i];
    __syncthreads();
    const int lo = t * 20;
    const int hi = (lo + 20 < NN) ? lo + 20 : NN;
    int sum = 0;
    for (int i = lo; i < hi; ++i) sum += c[i];
    s[t] = sum;
    __syncthreads();
    for (int off = 1; off < 1024; off <<= 1) {
        int v = (t >= off) ? s[t - off] : 0;
        __syncthreads();
        s[t] += v;
        __syncthreads();
    }
    int base = (t > 0) ? s[t - 1] : 0;
    for (int i = lo; i < hi; ++i) { int cv = c[i]; c[i] = base; base += cv; }
    __syncthreads();
    for (int i = t; i < NN; i += 1024) cursor[i] = c[i];
}

__global__ void scatter_perm(const int* __restrict__ dstI,
                             int* __restrict__ cursor, int* __restrict__ perm) {
    int e = blockIdx.x * 256 + threadIdx.x;
    if (e < NE) {
        int pos = atomicAdd(&cursor[dstI[e]], 1);
        perm[pos] = e;
    }
}

// ---------------------------------------------------------------- edge MLP
// R7-proven best: 512 threads / 64-edge tile, fragment-major W (coalesced
// 1KB weight loads), per-thread perm staging, nf prefetch in the acc1-dead
// register window, setprio around MFMA. 2 blocks/CU (66KB LDS union),
// exactly at the 128-reg/wave occupancy point. Structural plateau levers
// individually falsified: X-in-regs (R5 spill), direct-global X (R4 HBM
// blowup), split-K async stage (R8 null), 34KB/4-block variant (R5).
__global__ void __launch_bounds__(512, 4)
gine_edge(const float* __restrict__ edge_feat,
          const float* __restrict__ node_feat,
          const int* __restrict__ srcI,
          const int* __restrict__ dstI,
          const int* __restrict__ perm,
          const unsigned short* __restrict__ W1F,   // fragment-major [256 frags][1KB]
          const float* __restrict__ b1,             // [512]
          const unsigned short* __restrict__ W2F,   // fragment-major [256 frags][1KB]
          const float* __restrict__ b2,             // [256]
          float* __restrict__ out_h)                // [NN,256] fp32 accum
{
    __shared__ union {
        unsigned short Xs[64 * 264];   // staged bf16 input, +8 pad
        unsigned short Hs[64 * 512];   // XOR-swizzled hidden
        float          Msg[64 * 260];  // fp32 messages, +4 pad
    } sh;
    __shared__ int snS[64], dnS[64];

    const int tid  = threadIdx.x;
    const int wave = tid >> 6;       // 0..7
    const int lane = tid & 63;
    const int quad = lane >> 4;
    const int ln   = lane & 15;
    const int bs   = (blockIdx.x & 7) * 625 + (blockIdx.x >> 3);
    const int e0   = bs * 64;

    // ---- stage gathered edge_feat rows -> bf16 LDS (per-thread perm read)
    #pragma unroll
    for (int it = 0; it < 4; ++it) {
        const int chunk = tid + it * 512;          // 2048 chunks of 8 elems
        const int row = chunk >> 5;
        const int c8  = (chunk & 31) << 3;
        const int e   = perm[e0 + row];            // broadcast across 32 threads
        const float* p = edge_feat + (size_t)e * FIN + c8;
        f32x4 o0 = *(const f32x4*)(p);
        f32x4 o1 = *(const f32x4*)(p + 4);
        *(bf16x8*)(&sh.Xs[row * 264 + c8]) = cvt8(o0, o1);
    }
    if (tid < 64) {
        const int e = perm[e0 + tid];
        snS[tid] = srcI[e];
        dnS[tid] = dstI[e];
    }
    __syncthreads();

    // ---- layer 1 (swapped): D1[n][edge]; 8 waves x 64-wide N slices
    f32x4 zero4 = {0.f, 0.f, 0.f, 0.f};
    f32x4 acc1[4][4];                              // [n-tile][edge-tile]
    #pragma unroll
    for (int nt = 0; nt < 4; ++nt)
        #pragma unroll
        for (int et = 0; et < 4; ++et) acc1[nt][et] = zero4;

    __builtin_amdgcn_s_setprio(1);
    #pragma unroll
    for (int ks = 0; ks < 8; ++ks) {
        bf16x8 w[4], x[4];
        #pragma unroll
        for (int nt = 0; nt < 4; ++nt)            // frag (wave*4+nt, ks): 1KB lane-linear
            w[nt] = *(const bf16x8*)(W1F + (((wave * 4 + nt) * 8 + ks) * 64 + lane) * 8);
        #pragma unroll
        for (int et = 0; et < 4; ++et)
            x[et] = *(const bf16x8*)(&sh.Xs[(et * 16 + ln) * 264 + quad * 8 + ks * 32]);
        #pragma unroll
        for (int nt = 0; nt < 4; ++nt)
            #pragma unroll
            for (int et = 0; et < 4; ++et)
                acc1[nt][et] = mfma16(w[nt], x[et], acc1[nt][et]);
    }
    __builtin_amdgcn_s_setprio(0);
    __syncthreads();   // done reading Xs before overwriting Hs

    // bias + relu -> packed bf16x4 -> swizzled LDS
    #pragma unroll
    for (int nt = 0; nt < 4; ++nt) {
        const int n0 = wave * 64 + nt * 16 + quad * 4;     // 4 consecutive n
        const f32x4 b4 = *(const f32x4*)(b1 + n0);
        #pragma unroll
        for (int et = 0; et < 4; ++et) {
            const int edge = et * 16 + ln;
            u16x4 p = pack4(fmaxf(acc1[nt][et][0] + b4[0], 0.f),
                            fmaxf(acc1[nt][et][1] + b4[1], 0.f),
                            fmaxf(acc1[nt][et][2] + b4[2], 0.f),
                            fmaxf(acc1[nt][et][3] + b4[3], 0.f));
            *(u16x4*)(&sh.Hs[(edge << 9) + (((n0 >> 3) ^ (edge & 7)) << 3) + (n0 & 7)]) = p;
        }
    }
    __syncthreads();

    // ---- nf prefetch (T14): issue gathers now, consume after L2 MFMA.
    // acc1 is dead here, so the 32 VGPRs fit in its window.
    f32x4 nfr[2][4];
    #pragma unroll
    for (int nt = 0; nt < 2; ++nt) {
        const int n0 = wave * 32 + nt * 16 + quad * 4;
        #pragma unroll
        for (int et = 0; et < 4; ++et) {
            const int sn = snS[et * 16 + ln];
            nfr[nt][et] = *(const f32x4*)(node_feat + (size_t)sn * FIN + n0);
        }
    }

    // ---- layer 2 (swapped): D2[n][edge]; 8 waves x 32-wide N slices
    f32x4 acc2[2][4];                              // [n-tile][edge-tile]
    #pragma unroll
    for (int nt = 0; nt < 2; ++nt)
        #pragma unroll
        for (int et = 0; et < 4; ++et) acc2[nt][et] = zero4;

    __builtin_amdgcn_s_setprio(1);
    #pragma unroll
    for (int ks = 0; ks < 16; ++ks) {
        const int kb = ks * 4 + quad;
        bf16x8 w[2], h[4];
        #pragma unroll
        for (int nt = 0; nt < 2; ++nt)            // frag (wave*2+nt, ks)
            w[nt] = *(const bf16x8*)(W2F + (((wave * 2 + nt) * 16 + ks) * 64 + lane) * 8);
        #pragma unroll
        for (int et = 0; et < 4; ++et) {
            const int edge = et * 16 + ln;
            h[et] = *(const bf16x8*)(&sh.Hs[(edge << 9) + ((kb ^ (edge & 7)) << 3)]);
        }
        #pragma unroll
        for (int nt = 0; nt < 2; ++nt)
            #pragma unroll
            for (int et = 0; et < 4; ++et)
                acc2[nt][et] = mfma16(w[nt], h[et], acc2[nt][et]);
    }
    __builtin_amdgcn_s_setprio(0);
    __syncthreads();   // done reading Hs before overwriting Msg

    // ---- epilogue 1: msg = relu(nf + E) -> LDS (fp32), nf from prefetch regs
    #pragma unroll
    for (int nt = 0; nt < 2; ++nt) {
        const int n0 = wave * 32 + nt * 16 + quad * 4;
        const f32x4 b4 = *(const f32x4*)(b2 + n0);
        #pragma unroll
        for (int et = 0; et < 4; ++et) {
            const int edge = et * 16 + ln;
            f32x4 m;
            #pragma unroll
            for (int r = 0; r < 4; ++r)
                m[r] = fmaxf(nfr[nt][et][r] + acc2[nt][et][r] + b4[r], 0.f);
            *(f32x4*)(&sh.Msg[edge * 260 + n0]) = m;
        }
    }
    __syncthreads();

    // ---- epilogue 2: run-length reduce over sorted dst rows; 512 threads =
    // 2 half-scans of 32 rows per column. Runs touching a half boundary use
    // atomicAdd (correct vs zero-init); interior runs are exclusive -> store.
    {
        const int col  = tid & 255;
        const int half = tid >> 8;
        const int rA   = half * 32;
        const int dF = dnS[rA], dL = dnS[rA + 31];
        float run = sh.Msg[rA * 260 + col];
        int cur = dF;
        #pragma unroll 4
        for (int row = rA + 1; row < rA + 32; ++row) {
            const int d = dnS[row];
            if (d != cur) {
                if (cur == dF || cur == dL)
                    atomicAdd(&out_h[(size_t)cur * FIN + col], run);
                else
                    out_h[(size_t)cur * FIN + col] = run;
                run = 0.f;
                cur = d;
            }
            run += sh.Msg[row * 260 + col];
        }
        atomicAdd(&out_h[(size_t)cur * FIN + col], run);   // cur == dL
    }
}

// ---------------------------------------------------------------- node MLP
__global__ void __launch_bounds__(512, 4)
gine_node(const float* __restrict__ node_feat,
          const float* __restrict__ out_h,
          const unsigned short* __restrict__ W1F,   // fragment-major
          const float* __restrict__ b1,
          const unsigned short* __restrict__ W2F,   // fragment-major
          const float* __restrict__ b2,
          const float* __restrict__ eps,
          float* __restrict__ out)
{
    __shared__ union {
        unsigned short Xs[64 * 264];
        unsigned short Hs[64 * 512];
    } sh;

    const int tid  = threadIdx.x;
    const int wave = tid >> 6;       // 0..7
    const int lane = tid & 63;
    const int quad = lane >> 4;
    const int ln   = lane & 15;
    const int n0b  = blockIdx.x * 64;
    const float epsv = 1.0f + eps[0];

    // stage x = (1+eps)*node_feat + out_h  -> bf16 LDS
    #pragma unroll
    for (int it = 0; it < 4; ++it) {
        const int chunk = tid + it * 512;
        const int row = chunk >> 5;
        const int c8  = (chunk & 31) << 3;
        const int g   = n0b + row;
        bf16x8 pack = {0, 0, 0, 0, 0, 0, 0, 0};
        if (g < NN) {
            const float* pn = node_feat + (size_t)g * FIN + c8;
            const float* ph = out_h + (size_t)g * FIN + c8;
            f32x4 n0v = *(const f32x4*)(pn);
            f32x4 n1v = *(const f32x4*)(pn + 4);
            f32x4 h0v = *(const f32x4*)(ph);
            f32x4 h1v = *(const f32x4*)(ph + 4);
            f32x4 a, b;
            #pragma unroll
            for (int j = 0; j < 4; ++j) {
                a[j] = epsv * n0v[j] + h0v[j];
                b[j] = epsv * n1v[j] + h1v[j];
            }
            pack = cvt8(a, b);
        }
        *(bf16x8*)(&sh.Xs[row * 264 + c8]) = pack;
    }
    __syncthreads();

    // ---- layer 1 (swapped)
    f32x4 zero4 = {0.f, 0.f, 0.f, 0.f};
    f32x4 acc1[4][4];
    #pragma unroll
    for (int nt = 0; nt < 4; ++nt)
        #pragma unroll
        for (int et = 0; et < 4; ++et) acc1[nt][et] = zero4;

    __builtin_amdgcn_s_setprio(1);
    #pragma unroll
    for (int ks = 0; ks < 8; ++ks) {
        bf16x8 w[4], xv[4];
        #pragma unroll
        for (int nt = 0; nt < 4; ++nt)
            w[nt] = *(const bf16x8*)(W1F + (((wave * 4 + nt) * 8 + ks) * 64 + lane) * 8);
        #pragma unroll
        for (int et = 0; et < 4; ++et)
            xv[et] = *(const bf16x8*)(&sh.Xs[(et * 16 + ln) * 264 + quad * 8 + ks * 32]);
        #pragma unroll
        for (int nt = 0; nt < 4; ++nt)
            #pragma unroll
            for (int et = 0; et < 4; ++et)
                acc1[nt][et] = mfma16(w[nt], xv[et], acc1[nt][et]);
    }
    __builtin_amdgcn_s_setprio(0);
    __syncthreads();

    #pragma unroll
    for (int nt = 0; nt < 4; ++nt) {
        const int n0 = wave * 64 + nt * 16 + quad * 4;
        const f32x4 b4 = *(const f32x4*)(b1 + n0);
        #pragma unroll
        for (int et = 0; et < 4; ++et) {
            const int edge = et * 16 + ln;
            u16x4 p = pack4(fmaxf(acc1[nt][et][0] + b4[0], 0.f),
                            fmaxf(acc1[nt][et][1] + b4[1], 0.f),
                            fmaxf(acc1[nt][et][2] + b4[2], 0.f),
                            fmaxf(acc1[nt][et][3] + b4[3], 0.f));
            *(u16x4*)(&sh.Hs[(edge << 9) + (((n0 >> 3) ^ (edge & 7)) << 3) + (n0 & 7)]) = p;
        }
    }
    __syncthreads();

    // ---- layer 2 (swapped)
    f32x4 acc2[2][4];
    #pragma unroll
    for (int nt = 0; nt < 2; ++nt)
        #pragma unroll
        for (int et = 0; et < 4; ++et) acc2[nt][et] = zero4;

    __builtin_amdgcn_s_setprio(1);
    #pragma unroll
    for (int ks = 0; ks < 16; ++ks) {
        const int kb = ks * 4 + quad;
        bf16x8 w[2], h[4];
        #pragma unroll
        for (int nt = 0; nt < 2; ++nt)
            w[nt] = *(const bf16x8*)(W2F + (((wave * 2 + nt) * 16 + ks) * 64 + lane) * 8);
        #pragma unroll
        for (int et = 0; et < 4; ++et) {
            const int edge = et * 16 + ln;
            h[et] = *(const bf16x8*)(&sh.Hs[(edge << 9) + ((kb ^ (edge & 7)) << 3)]);
        }
        #pragma unroll
        for (int nt = 0; nt < 2; ++nt)
            #pragma unroll
            for (int et = 0; et < 4; ++et)
                acc2[nt][et] = mfma16(w[nt], h[et], acc2[nt][et]);
    }
    __builtin_amdgcn_s_setprio(0);

    // C-write: 16-B vector stores
    #pragma unroll
    for (int nt = 0; nt < 2; ++nt) {
        const int n0 = wave * 32 + nt * 16 + quad * 4;
        const f32x4 b4 = *(const f32x4*)(b2 + n0);
        #pragma unroll
        for (int et = 0; et < 4; ++et) {
            const int g = n0b + et * 16 + ln;
            if (g < NN) {
                f32x4 o;
                #pragma unroll
                for (int r = 0; r < 4; ++r)
                    o[r] = acc2[nt][et][r] + b4[r];
                *(f32x4*)(out + (size_t)g * FIN + n0) = o;
            }
        }
    }
}

// ---------------------------------------------------------------- launch
extern "C" void kernel_launch(void* const* d_in, const int* in_sizes, int n_in,
                              void* d_out, int out_size, void* d_ws, size_t ws_size,
                              hipStream_t stream) {
    const float* node_feat = (const float*)d_in[0];
    const float* edge_feat = (const float*)d_in[1];
    const int* srcI = (const int*)d_in[2];
    const int* dstI = (const int*)d_in[3];
    const float* We1 = (const float*)d_in[4];
    const float* be1 = (const float*)d_in[5];
    const float* We2 = (const float*)d_in[6];
    const float* be2 = (const float*)d_in[7];
    const float* Wn1 = (const float*)d_in[8];
    const float* bn1 = (const float*)d_in[9];
    const float* Wn2 = (const float*)d_in[10];
    const float* bn2 = (const float*)d_in[11];
    const float* eps = (const float*)d_in[12];

    char* ws = (char*)d_ws;
    float* out_h = (float*)ws;                                  // 20,480,000 B
    unsigned short* W1F  = (unsigned short*)(ws + 20480000);    // 256 KB each
    unsigned short* W2F  = W1F + 131072;
    unsigned short* Wn1F = W2F + 131072;
    unsigned short* Wn2F = Wn1F + 131072;
    int* cnt    = (int*)(ws + 20480000 + 4 * 262144);           // 80 KB
    int* cursor = cnt + NN;                                     // 80 KB
    int* perm   = cursor + NN;                                  // 1.25 MB

    hipMemsetAsync(out_h, 0, (size_t)NN * FIN * sizeof(float), stream);
    hipMemsetAsync(cnt, 0, NN * sizeof(int), stream);

    prep_hist<<<1280, 256, 0, stream>>>(We1, We2, Wn1, Wn2, dstI,
                                        W1F, W2F, Wn1F, Wn2F, cnt);
    scan_excl<<<1, 1024, 0, stream>>>(cnt, cursor);
    scatter_perm<<<(NE + 255) / 256, 256, 0, stream>>>(dstI, cursor, perm);

    gine_edge<<<NE / 64, 512, 0, stream>>>(edge_feat, node_feat, srcI, dstI,
                                           perm, W1F, be1, W2F, be2, out_h);
    gine_node<<<(NN + 63) / 64, 512, 0, stream>>>(node_feat, out_h, Wn1F, bn1,
                                                  Wn2F, bn2, eps, (float*)d_out);
}